// Round 7
// baseline (484.039 us; speedup 1.0000x reference)
//
#include <hip/hip_runtime.h>
#include <stdint.h>

// B=8, W=1024, D=1024, H=16, KD=VD=64
// QK buffer: rows = token (8192), cols = proj*1024 + h*64 + d (2048; Q,K only, bf16)
// Vt[bh][d][m] fp16, written transposed from the GEMM epilogue.
// Q pre-scaled by 0.125*log2(e) (softmax in exp2 domain).
//
// gemm_qkv: BM=256 BN=192 BK=64, 16 waves (4Mx4N grid, 64x48 per wave),
// 4 waves/SIMD; 2 phases per K-tile; 3-bit XOR swizzle (0 conflicts, R2);
// counted vmcnt (never drain-0 in loop).
//
// attn R7: NO LDS AT ALL. K/V per (b,h) = 256KB, L2-resident (XCD swizzle
// keeps one bh's q-blocks on one XCD); the 4 waves of a block read the same
// 16KB tile near-simultaneously -> L1 serves the intra-block duplication
// (m169 precedent: direct-from-L2 beat staging +26% at S=1024).
// Removes: 16KB/wave/tile LDS reads, 8.4M conflict cy, 2 barriers/tile, DMA.
// No barriers anywhere; loads hoisted by compiler under vmcnt; 4 waves/SIMD.

using bf16x8 = __attribute__((ext_vector_type(8))) __bf16;
using f32x4  = __attribute__((ext_vector_type(4))) float;
using f16x4  = __attribute__((ext_vector_type(4))) _Float16;

union frag_u  { uint4 u4; bf16x8 f; };
union vfrag_u { uint2 u2; f16x4 f; };
union pfrag_u { unsigned int u[2]; f16x4 f; };

__device__ inline unsigned short f2bf(float x){
  unsigned int u = __float_as_uint(x);
  u += 0x7fffu + ((u >> 16) & 1u);      // round-to-nearest-even
  return (unsigned short)(u >> 16);
}

__device__ inline unsigned int pkrtz_u32(float a, float b){
  auto r = __builtin_amdgcn_cvt_pkrtz(a, b);   // __fp16 ext_vector(2)
  unsigned int u; __builtin_memcpy(&u, &r, 4); return u;
}

__device__ inline void gl_lds16(const void* g, void* l){
  __builtin_amdgcn_global_load_lds(
      (const __attribute__((address_space(1))) void*)g,
      (__attribute__((address_space(3))) void*)l, 16, 0, 0);
}

#define SBAR() do{ asm volatile("" ::: "memory"); __builtin_amdgcn_s_barrier(); asm volatile("" ::: "memory"); }while(0)
#define VMC(n)  asm volatile("s_waitcnt vmcnt(" #n ")" ::: "memory")

// ---------------- kernel 1: fused input & weight cast ----------------
// blocks [0,8192): X fp32->bf16.  blocks [8192,8960): W transpose+cast.
__global__ void cast_all(const float* __restrict__ X,
                         const float* __restrict__ Wq, const float* __restrict__ Wk,
                         const float* __restrict__ Wv,
                         unsigned short* __restrict__ Xb,
                         unsigned short* __restrict__ Wt){
  __shared__ float tile[64][65];
  int bid = blockIdx.x;
  if (bid < 8192){
    int i = (bid * 256 + threadIdx.x) * 4;
    float4 v = *(const float4*)(X + i);
    ushort4 o;
    o.x = f2bf(v.x); o.y = f2bf(v.y); o.z = f2bf(v.z); o.w = f2bf(v.w);
    *(ushort4*)(Xb + i) = o;
    return;
  }
  int id = bid - 8192;            // 0..767
  int proj = id >> 8;
  int rem  = id & 255;
  int kt = rem & 15, nt = rem >> 4;
  const float* Wsrc = (proj == 0) ? Wq : ((proj == 1) ? Wk : Wv);
  int k0 = kt * 64, n0 = nt * 64;
  int tx = threadIdx.x & 63, ty = threadIdx.x >> 6;   // ty 0..3
  for (int i = 0; i < 16; i++){
    int k = i * 4 + ty;
    tile[k][tx] = Wsrc[(k0 + k) * 1024 + n0 + tx];
  }
  __syncthreads();
  for (int i = 0; i < 16; i++){
    int n = i * 4 + ty;
    Wt[(proj * 1024 + n0 + n) * 1024 + k0 + tx] = f2bf(tile[tx][n]);
  }
}

// ---------------- kernel 2: fused QKV GEMM ----------------
__global__ __launch_bounds__(1024, 4) void gemm_qkv(
    const unsigned short* __restrict__ Xb,
    const unsigned short* __restrict__ Wt,
    unsigned short* __restrict__ QK,
    unsigned short* __restrict__ Vt){
  __shared__ __align__(16) char Abuf[2][32768];   // [buf][256 rows x 64 k] bf16, swizzled
  __shared__ __align__(16) char Bbuf[2][24576];   // [buf][192 rows x 64 k] bf16, swizzled

  int bid = blockIdx.x;                      // 512
  int tau = (bid & 7) * 64 + (bid >> 3);     // XCD swizzle (512 % 8 == 0, bijective)
  int by = tau >> 4, bx = tau & 15;          // by: m-tile (32), bx: n-tile (16)
  int tid = threadIdx.x;
  int w = tid >> 6, lane = tid & 63;
  int li = lane & 15, g = lane >> 4;
  int lrow = lane >> 3;                      // 0..7 (dest row within 8-lane cluster)
  int wr = w >> 2, wc = w & 3;               // 4 x 4 wave grid, wave tile 64x48
  int wu = __builtin_amdgcn_readfirstlane(w);

  // staging source offsets (elements): inverse of byte ^= (row&7)<<4.
  int xcol = ((lane & 7) ^ lrow) << 3;
  int aoff0 = (by * 256 + w * 8 + lrow) * 1024 + xcol;          // A segs 0..15
  int aoff1 = (by * 256 + (16 + w) * 8 + lrow) * 1024 + xcol;   // A segs 16..31
  int bseg0 = (w < 8) ? w : (w + 8);         // B segs: w<8 -> {w, w+8}; w>=8 -> {w+8}
  int bseg1 = w + 8;
  int boff0 = (bx * 192 + bseg0 * 8 + lrow) * 1024 + xcol;
  int boff1 = (bx * 192 + bseg1 * 8 + lrow) * 1024 + xcol;      // only w<8

  // ds_read addressing (bytes): physical = row*128 + ((kk*64+g*16) ^ ((row&7)<<4))
  int swz  = (li & 7) << 4;
  int colA0 = (g * 16) ^ swz;
  int colA1 = (64 + g * 16) ^ swz;
  int aBase = (wr * 64 + li) * 128;
  int bBase = (wc * 48 + li) * 128;

  f32x4 acc[4][3] = {};
  frag_u bfr[3][2], af[2][2];

#define LDB(buf) do{ \
  _Pragma("unroll") for (int n = 0; n < 3; n++){ \
    bfr[n][0].u4 = *(const uint4*)&Bbuf[buf][bBase + n * 2048 + colA0]; \
    bfr[n][1].u4 = *(const uint4*)&Bbuf[buf][bBase + n * 2048 + colA1]; } }while(0)
#define LDA2(buf, m0) do{ \
  af[0][0].u4 = *(const uint4*)&Abuf[buf][aBase + (m0)     * 2048 + colA0]; \
  af[0][1].u4 = *(const uint4*)&Abuf[buf][aBase + (m0)     * 2048 + colA1]; \
  af[1][0].u4 = *(const uint4*)&Abuf[buf][aBase + (m0 + 1) * 2048 + colA0]; \
  af[1][1].u4 = *(const uint4*)&Abuf[buf][aBase + (m0 + 1) * 2048 + colA1]; }while(0)
#define MFMA6(P) do{ __builtin_amdgcn_s_setprio(1); \
  _Pragma("unroll") for (int kk = 0; kk < 2; kk++) \
  _Pragma("unroll") for (int i = 0; i < 2; i++) \
  _Pragma("unroll") for (int n = 0; n < 3; n++) \
    acc[(P) + i][n] = __builtin_amdgcn_mfma_f32_16x16x32_bf16( \
        af[i][kk].f, bfr[n][kk].f, acc[(P) + i][n], 0, 0, 0); \
  __builtin_amdgcn_s_setprio(0); }while(0)

  // prologue: B(0), A(0), B(1); wait so tile0 resident, B(1) in flight
  gl_lds16(Wt + boff0, &Bbuf[0][bseg0 * 1024]);
  if (wu < 8) gl_lds16(Wt + boff1, &Bbuf[0][bseg1 * 1024]);
  gl_lds16(Xb + aoff0, &Abuf[0][w * 1024]);
  gl_lds16(Xb + aoff1, &Abuf[0][(16 + w) * 1024]);
  gl_lds16(Wt + boff0 + 64, &Bbuf[1][bseg0 * 1024]);
  if (wu < 8){
    gl_lds16(Wt + boff1 + 64, &Bbuf[1][bseg1 * 1024]);
    VMC(2);
  } else {
    VMC(1);
  }
  SBAR();

  for (int t = 0; t < 16; ++t){
    int cur = t & 1, nxt = cur ^ 1;
    // ---- phase 0: read B + A(mi 0-1), stage A(t+1), MFMA mi 0-1
    LDB(cur);
    LDA2(cur, 0);
    if (t < 15){
      gl_lds16(Xb + aoff0 + (t + 1) * 64, &Abuf[nxt][w * 1024]);
      gl_lds16(Xb + aoff1 + (t + 1) * 64, &Abuf[nxt][(16 + w) * 1024]);
    }
    MFMA6(0);                 // consumes all phase-0 ds_reads before barrier
    SBAR();
    // ---- phase 1: read A(mi 2-3), stage B(t+2) (Bbuf[cur]: B-reads all done
    // at phase 0 and every wave is past the phase-0 barrier -> safe), MFMA mi 2-3
    LDA2(cur, 2);
    if (t < 14){
      gl_lds16(Wt + boff0 + (t + 2) * 64, &Bbuf[cur][bseg0 * 1024]);
      if (wu < 8) gl_lds16(Wt + boff1 + (t + 2) * 64, &Bbuf[cur][bseg1 * 1024]);
    }
    MFMA6(2);
    if (t < 14){
      if (wu < 8) { VMC(2); } else { VMC(1); }   // leave only B(t+2) in flight
    } else if (t == 14) {
      VMC(0);                                    // final drain: tile 15 resident
    }
    SBAR();
  }
#undef LDB
#undef LDA2
#undef MFMA6

  // epilogue: frag (mi,n): row = by*256 + wr*64 + mi*16 + g*4 + r, col = cb + li
  int row0 = by * 256 + wr * 64 + g * 4;
  int bb16 = (by >> 2) * 16;
#pragma unroll
  for (int n = 0; n < 3; n++){
    int cb = bx * 192 + wc * 48 + n * 16;     // wave-uniform frag col base
    if (cb < 2048){
      float sc = (cb < 1024) ? 0.1803368801111f : 1.0f;  // 0.125*log2(e) on Q
#pragma unroll
      for (int m = 0; m < 4; m++){
        int row = row0 + m * 16;
#pragma unroll
        for (int r = 0; r < 4; r++)
          QK[(size_t)(row + r) * 2048 + cb + li] = f2bf(acc[m][n][r] * sc);
      }
    } else {
      int vc = cb + li - 2048;                // v-column 0..1023
      int hh = vc >> 6, dd = vc & 63;
#pragma unroll
      for (int m = 0; m < 4; m++){
        int mtok = (row0 + m * 16) & 1023;
        uint2 cv;
        cv.x = pkrtz_u32(acc[m][n][0], acc[m][n][1]);
        cv.y = pkrtz_u32(acc[m][n][2], acc[m][n][3]);
        *(uint2*)(Vt + ((size_t)(bb16 + hh) * 64 + dd) * 1024 + mtok) = cv;
      }
    }
  }
}

// ---------------- kernel 3: flash attention (LDS-free) ----------------
// block = (b, h, qb): 4 waves x 16 q = 64 q per block; m-tiles of 64.
// 2048 blocks; launch_bounds(256,4); no LDS, no barriers.
// K frag (m,d): Kg + m*2048 + d, d = c*32 + g*8 + j  (64B-coalesced per row).
// V frag (d,m): Vg + d*1024 + m, d = tv*16+li, m = m0 + t*16 + g*4.
// XCD swizzle: bh = id&127 so q-blocks of one (b,h) share id%8 (same XCD L2).
__global__ __launch_bounds__(256, 4) void attn(const unsigned short* __restrict__ QK,
                                               const unsigned short* __restrict__ Vt,
                                               float* __restrict__ Out){
  int id = blockIdx.x;                  // 2048
  int bh = id & 127, qb = id >> 7;      // qb 0..15
  int b = bh >> 4, h = bh & 15;
  int w = threadIdx.x >> 6, lane = threadIdx.x & 63;
  int g = lane >> 4, li = lane & 15;

  // Q B-frags (bf16): lane li holds col q, k = c*32 + g*8 + j
  frag_u qf[2];
  {
    int tok = b * 1024 + qb * 64 + w * 16 + li;
    const unsigned short* qp = QK + (size_t)tok * 2048 + h * 64 + g * 8;
    qf[0].u4 = *(const uint4*)(qp);
    qf[1].u4 = *(const uint4*)(qp + 32);
  }

  f32x4 o[4] = {};             // O^T tiles: row v = tv*16+g*4+r, col q = li
  f32x4 osum = {};             // ones-row PV accumulator: every entry = psum[q=li]
  const f32x4 bias = {-10.f, -10.f, -10.f, -10.f};   // fp16-overflow guard
  pfrag_u ones;                // all-ones fp16 A-frag for the denominator MFMA
  ones.u[0] = 0x3c003c00u; ones.u[1] = 0x3c003c00u;

  const unsigned short* Kg = QK + (size_t)b * 1024 * 2048 + 1024 + h * 64;
  const unsigned short* Vg = Vt + (size_t)bh * 65536;

  // per-t K row pointers (row = t*16 + li, advances 64 rows/mt) and
  // per-tv V row pointers (row d = tv*16 + li, col advances 64/mt)
  const unsigned short* kp0 = Kg + (size_t)(0 * 16 + li) * 2048 + g * 8;
  const unsigned short* kp1 = Kg + (size_t)(1 * 16 + li) * 2048 + g * 8;
  const unsigned short* kp2 = Kg + (size_t)(2 * 16 + li) * 2048 + g * 8;
  const unsigned short* kp3 = Kg + (size_t)(3 * 16 + li) * 2048 + g * 8;
  const unsigned short* vp0 = Vg + (0 * 16 + li) * 1024 + g * 4;
  const unsigned short* vp1 = Vg + (1 * 16 + li) * 1024 + g * 4;
  const unsigned short* vp2 = Vg + (2 * 16 + li) * 1024 + g * 4;
  const unsigned short* vp3 = Vg + (3 * 16 + li) * 1024 + g * 4;

  for (int mt = 0; mt < 16; mt++){
    // S^T = K Q^T - 10 : A-frag = K rows (m) direct from L1/L2, B-frag = Q (regs)
    f32x4 s0 = bias, s1 = bias, s2 = bias, s3 = bias;
    frag_u k00, k01, k10, k11, k20, k21, k30, k31;
    k00.u4 = *(const uint4*)(kp0);  k01.u4 = *(const uint4*)(kp0 + 32);
    k10.u4 = *(const uint4*)(kp1);  k11.u4 = *(const uint4*)(kp1 + 32);
    k20.u4 = *(const uint4*)(kp2);  k21.u4 = *(const uint4*)(kp2 + 32);
    k30.u4 = *(const uint4*)(kp3);  k31.u4 = *(const uint4*)(kp3 + 32);
    __builtin_amdgcn_s_setprio(1);
    s0 = __builtin_amdgcn_mfma_f32_16x16x32_bf16(k00.f, qf[0].f, s0, 0, 0, 0);
    s0 = __builtin_amdgcn_mfma_f32_16x16x32_bf16(k01.f, qf[1].f, s0, 0, 0, 0);
    s1 = __builtin_amdgcn_mfma_f32_16x16x32_bf16(k10.f, qf[0].f, s1, 0, 0, 0);
    s1 = __builtin_amdgcn_mfma_f32_16x16x32_bf16(k11.f, qf[1].f, s1, 0, 0, 0);
    s2 = __builtin_amdgcn_mfma_f32_16x16x32_bf16(k20.f, qf[0].f, s2, 0, 0, 0);
    s2 = __builtin_amdgcn_mfma_f32_16x16x32_bf16(k21.f, qf[1].f, s2, 0, 0, 0);
    s3 = __builtin_amdgcn_mfma_f32_16x16x32_bf16(k30.f, qf[0].f, s3, 0, 0, 0);
    s3 = __builtin_amdgcn_mfma_f32_16x16x32_bf16(k31.f, qf[1].f, s3, 0, 0, 0);
    __builtin_amdgcn_s_setprio(0);

    // P = exp2(S^T); lane holds P[q=li][m = t*16 + g*4 + r] == B-frag(k = g*4+e)
    // of mfma_f32_16x16x16f16 for k-chunk t. Pack straight into registers.
    pfrag_u pf[4];
    {
      f32x4 sarr[4] = {s0, s1, s2, s3};
#pragma unroll
      for (int t = 0; t < 4; t++){
        float p0 = __builtin_exp2f(sarr[t][0]);
        float p1 = __builtin_exp2f(sarr[t][1]);
        float p2 = __builtin_exp2f(sarr[t][2]);
        float p3 = __builtin_exp2f(sarr[t][3]);
        pf[t].u[0] = pkrtz_u32(p0, p1);
        pf[t].u[1] = pkrtz_u32(p2, p3);
      }
    }

    // O^T += V^T P^T ; denominator row via ones-A MFMA (column sums of P).
    __builtin_amdgcn_s_setprio(1);
#pragma unroll
    for (int t = 0; t < 4; t++)
      osum = __builtin_amdgcn_mfma_f32_16x16x16f16(ones.f, pf[t].f, osum, 0, 0, 0);
#pragma unroll
    for (int t = 0; t < 4; t++){
      vfrag_u v0, v1, v2, v3;
      v0.u2 = *(const uint2*)(vp0 + t * 16);
      v1.u2 = *(const uint2*)(vp1 + t * 16);
      v2.u2 = *(const uint2*)(vp2 + t * 16);
      v3.u2 = *(const uint2*)(vp3 + t * 16);
      o[0] = __builtin_amdgcn_mfma_f32_16x16x16f16(v0.f, pf[t].f, o[0], 0, 0, 0);
      o[1] = __builtin_amdgcn_mfma_f32_16x16x16f16(v1.f, pf[t].f, o[1], 0, 0, 0);
      o[2] = __builtin_amdgcn_mfma_f32_16x16x16f16(v2.f, pf[t].f, o[2], 0, 0, 0);
      o[3] = __builtin_amdgcn_mfma_f32_16x16x16f16(v3.f, pf[t].f, o[3], 0, 0, 0);
    }
    __builtin_amdgcn_s_setprio(0);

    kp0 += 64 * 2048; kp1 += 64 * 2048; kp2 += 64 * 2048; kp3 += 64 * 2048;
    vp0 += 64; vp1 += 64; vp2 += 64; vp3 += 64;
  }

  // denominator: osum rows are all identical = sum_m P[q=li][m]
  float inv = 1.f / osum[0];

  // epilogue: lane holds O^T[v = tv*16+g*4+r][q=li] -> Out[b,q,h,v]; v contiguous
  int tok = b * 1024 + qb * 64 + w * 16 + li;
  float* op = Out + (size_t)tok * 1024 + h * 64 + g * 4;
  for (int tv = 0; tv < 4; tv++){
    float4 v4;
    v4.x = o[tv][0] * inv; v4.y = o[tv][1] * inv;
    v4.z = o[tv][2] * inv; v4.w = o[tv][3] * inv;
    *(float4*)(op + tv * 16) = v4;
  }
}

extern "C" void kernel_launch(void* const* d_in, const int* in_sizes, int n_in,
                              void* d_out, int out_size, void* d_ws, size_t ws_size,
                              hipStream_t stream) {
  const float* X  = (const float*)d_in[0];
  const float* Wq = (const float*)d_in[1];
  const float* Wk = (const float*)d_in[2];
  const float* Wv = (const float*)d_in[3];
  float* Out = (float*)d_out;
  char* ws = (char*)d_ws;
  // workspace layout (bytes): Xb 16MB | Wt 6MB | QK 32MB | Vt 16MB  (total 70MB)
  unsigned short* Xb = (unsigned short*)(ws);
  unsigned short* Wt = (unsigned short*)(ws + (size_t)16 * 1024 * 1024);
  unsigned short* QK = (unsigned short*)(ws + (size_t)22 * 1024 * 1024);
  unsigned short* Vt = (unsigned short*)(ws + (size_t)54 * 1024 * 1024);

  cast_all<<<8960, 256, 0, stream>>>(X, Wq, Wk, Wv, Xb, Wt);
  gemm_qkv<<<512, 1024, 0, stream>>>(Xb, Wt, QK, Vt);
  attn    <<<2048, 256, 0, stream>>>(QK, Vt, Out);
}

// Round 8
// 208.319 us; speedup vs baseline: 2.3235x; 2.3235x over previous
//
#include <hip/hip_runtime.h>
#include <stdint.h>

// B=8, W=1024, D=1024, H=16, KD=VD=64
// QK buffer: rows = token (8192), cols = proj*1024 + h*64 + d (2048; Q,K only, bf16)
// Vt[bh][d][m] fp16, written transposed from the GEMM epilogue.
// Q pre-scaled by 0.125*log2(e) (softmax in exp2 domain).
//
// gemm_qkv: BM=256 BN=192 BK=64, 16 waves (4Mx4N grid, 64x48 per wave),
// 4 waves/SIMD; 2 phases per K-tile; 3-bit XOR swizzle (0 conflicts, R2);
// counted vmcnt (never drain-0 in loop).
//
// attn R8: R3's verified 67us structure (syncthreads staging, (256,4), no
// setprio) + ONE change: each wave processes TWO q-groups (32 q). K/V frag
// reads are q-invariant, so each LDS read feeds 2 MFMAs -> LDS bytes/q HALVE
// (R3 counters: LDS read BW was the binding ~3500/5000 cy term). Block = 128q,
// grid = 1024 = 4 blocks/CU x 256 CU = ONE round (was two).
// R7 lesson (ledger): per-lane fragment gathers from global = 16 cache lines
// per vmem inst -> TA-bound, 5x slower. global_load_lds staging IS the
// coalescer; keep it.

using bf16x8 = __attribute__((ext_vector_type(8))) __bf16;
using f32x4  = __attribute__((ext_vector_type(4))) float;
using f16x4  = __attribute__((ext_vector_type(4))) _Float16;

union frag_u  { uint4 u4; bf16x8 f; };
union vfrag_u { uint2 u2; f16x4 f; };
union pfrag_u { unsigned int u[2]; f16x4 f; };

__device__ inline unsigned short f2bf(float x){
  unsigned int u = __float_as_uint(x);
  u += 0x7fffu + ((u >> 16) & 1u);      // round-to-nearest-even
  return (unsigned short)(u >> 16);
}

__device__ inline unsigned int pkrtz_u32(float a, float b){
  auto r = __builtin_amdgcn_cvt_pkrtz(a, b);   // __fp16 ext_vector(2)
  unsigned int u; __builtin_memcpy(&u, &r, 4); return u;
}

__device__ inline void gl_lds16(const void* g, void* l){
  __builtin_amdgcn_global_load_lds(
      (const __attribute__((address_space(1))) void*)g,
      (__attribute__((address_space(3))) void*)l, 16, 0, 0);
}

#define SBAR() do{ asm volatile("" ::: "memory"); __builtin_amdgcn_s_barrier(); asm volatile("" ::: "memory"); }while(0)
#define VMC(n)  asm volatile("s_waitcnt vmcnt(" #n ")" ::: "memory")

// ---------------- kernel 1: fused input & weight cast ----------------
// blocks [0,8192): X fp32->bf16.  blocks [8192,8960): W transpose+cast.
__global__ void cast_all(const float* __restrict__ X,
                         const float* __restrict__ Wq, const float* __restrict__ Wk,
                         const float* __restrict__ Wv,
                         unsigned short* __restrict__ Xb,
                         unsigned short* __restrict__ Wt){
  __shared__ float tile[64][65];
  int bid = blockIdx.x;
  if (bid < 8192){
    int i = (bid * 256 + threadIdx.x) * 4;
    float4 v = *(const float4*)(X + i);
    ushort4 o;
    o.x = f2bf(v.x); o.y = f2bf(v.y); o.z = f2bf(v.z); o.w = f2bf(v.w);
    *(ushort4*)(Xb + i) = o;
    return;
  }
  int id = bid - 8192;            // 0..767
  int proj = id >> 8;
  int rem  = id & 255;
  int kt = rem & 15, nt = rem >> 4;
  const float* Wsrc = (proj == 0) ? Wq : ((proj == 1) ? Wk : Wv);
  int k0 = kt * 64, n0 = nt * 64;
  int tx = threadIdx.x & 63, ty = threadIdx.x >> 6;   // ty 0..3
  for (int i = 0; i < 16; i++){
    int k = i * 4 + ty;
    tile[k][tx] = Wsrc[(k0 + k) * 1024 + n0 + tx];
  }
  __syncthreads();
  for (int i = 0; i < 16; i++){
    int n = i * 4 + ty;
    Wt[(proj * 1024 + n0 + n) * 1024 + k0 + tx] = f2bf(tile[tx][n]);
  }
}

// ---------------- kernel 2: fused QKV GEMM ----------------
__global__ __launch_bounds__(1024, 4) void gemm_qkv(
    const unsigned short* __restrict__ Xb,
    const unsigned short* __restrict__ Wt,
    unsigned short* __restrict__ QK,
    unsigned short* __restrict__ Vt){
  __shared__ __align__(16) char Abuf[2][32768];   // [buf][256 rows x 64 k] bf16, swizzled
  __shared__ __align__(16) char Bbuf[2][24576];   // [buf][192 rows x 64 k] bf16, swizzled

  int bid = blockIdx.x;                      // 512
  int tau = (bid & 7) * 64 + (bid >> 3);     // XCD swizzle (512 % 8 == 0, bijective)
  int by = tau >> 4, bx = tau & 15;          // by: m-tile (32), bx: n-tile (16)
  int tid = threadIdx.x;
  int w = tid >> 6, lane = tid & 63;
  int li = lane & 15, g = lane >> 4;
  int lrow = lane >> 3;                      // 0..7 (dest row within 8-lane cluster)
  int wr = w >> 2, wc = w & 3;               // 4 x 4 wave grid, wave tile 64x48
  int wu = __builtin_amdgcn_readfirstlane(w);

  // staging source offsets (elements): inverse of byte ^= (row&7)<<4.
  int xcol = ((lane & 7) ^ lrow) << 3;
  int aoff0 = (by * 256 + w * 8 + lrow) * 1024 + xcol;          // A segs 0..15
  int aoff1 = (by * 256 + (16 + w) * 8 + lrow) * 1024 + xcol;   // A segs 16..31
  int bseg0 = (w < 8) ? w : (w + 8);         // B segs: w<8 -> {w, w+8}; w>=8 -> {w+8}
  int bseg1 = w + 8;
  int boff0 = (bx * 192 + bseg0 * 8 + lrow) * 1024 + xcol;
  int boff1 = (bx * 192 + bseg1 * 8 + lrow) * 1024 + xcol;      // only w<8

  // ds_read addressing (bytes): physical = row*128 + ((kk*64+g*16) ^ ((row&7)<<4))
  int swz  = (li & 7) << 4;
  int colA0 = (g * 16) ^ swz;
  int colA1 = (64 + g * 16) ^ swz;
  int aBase = (wr * 64 + li) * 128;
  int bBase = (wc * 48 + li) * 128;

  f32x4 acc[4][3] = {};
  frag_u bfr[3][2], af[2][2];

#define LDB(buf) do{ \
  _Pragma("unroll") for (int n = 0; n < 3; n++){ \
    bfr[n][0].u4 = *(const uint4*)&Bbuf[buf][bBase + n * 2048 + colA0]; \
    bfr[n][1].u4 = *(const uint4*)&Bbuf[buf][bBase + n * 2048 + colA1]; } }while(0)
#define LDA2(buf, m0) do{ \
  af[0][0].u4 = *(const uint4*)&Abuf[buf][aBase + (m0)     * 2048 + colA0]; \
  af[0][1].u4 = *(const uint4*)&Abuf[buf][aBase + (m0)     * 2048 + colA1]; \
  af[1][0].u4 = *(const uint4*)&Abuf[buf][aBase + (m0 + 1) * 2048 + colA0]; \
  af[1][1].u4 = *(const uint4*)&Abuf[buf][aBase + (m0 + 1) * 2048 + colA1]; }while(0)
#define MFMA6(P) do{ __builtin_amdgcn_s_setprio(1); \
  _Pragma("unroll") for (int kk = 0; kk < 2; kk++) \
  _Pragma("unroll") for (int i = 0; i < 2; i++) \
  _Pragma("unroll") for (int n = 0; n < 3; n++) \
    acc[(P) + i][n] = __builtin_amdgcn_mfma_f32_16x16x32_bf16( \
        af[i][kk].f, bfr[n][kk].f, acc[(P) + i][n], 0, 0, 0); \
  __builtin_amdgcn_s_setprio(0); }while(0)

  // prologue: B(0), A(0), B(1); wait so tile0 resident, B(1) in flight
  gl_lds16(Wt + boff0, &Bbuf[0][bseg0 * 1024]);
  if (wu < 8) gl_lds16(Wt + boff1, &Bbuf[0][bseg1 * 1024]);
  gl_lds16(Xb + aoff0, &Abuf[0][w * 1024]);
  gl_lds16(Xb + aoff1, &Abuf[0][(16 + w) * 1024]);
  gl_lds16(Wt + boff0 + 64, &Bbuf[1][bseg0 * 1024]);
  if (wu < 8){
    gl_lds16(Wt + boff1 + 64, &Bbuf[1][bseg1 * 1024]);
    VMC(2);
  } else {
    VMC(1);
  }
  SBAR();

  for (int t = 0; t < 16; ++t){
    int cur = t & 1, nxt = cur ^ 1;
    // ---- phase 0: read B + A(mi 0-1), stage A(t+1), MFMA mi 0-1
    LDB(cur);
    LDA2(cur, 0);
    if (t < 15){
      gl_lds16(Xb + aoff0 + (t + 1) * 64, &Abuf[nxt][w * 1024]);
      gl_lds16(Xb + aoff1 + (t + 1) * 64, &Abuf[nxt][(16 + w) * 1024]);
    }
    MFMA6(0);                 // consumes all phase-0 ds_reads before barrier
    SBAR();
    // ---- phase 1: read A(mi 2-3), stage B(t+2) (Bbuf[cur]: B-reads all done
    // at phase 0 and every wave is past the phase-0 barrier -> safe), MFMA mi 2-3
    LDA2(cur, 2);
    if (t < 14){
      gl_lds16(Wt + boff0 + (t + 2) * 64, &Bbuf[cur][bseg0 * 1024]);
      if (wu < 8) gl_lds16(Wt + boff1 + (t + 2) * 64, &Bbuf[cur][bseg1 * 1024]);
    }
    MFMA6(2);
    if (t < 14){
      if (wu < 8) { VMC(2); } else { VMC(1); }   // leave only B(t+2) in flight
    } else if (t == 14) {
      VMC(0);                                    // final drain: tile 15 resident
    }
    SBAR();
  }
#undef LDB
#undef LDA2
#undef MFMA6

  // epilogue: frag (mi,n): row = by*256 + wr*64 + mi*16 + g*4 + r, col = cb + li
  int row0 = by * 256 + wr * 64 + g * 4;
  int bb16 = (by >> 2) * 16;
#pragma unroll
  for (int n = 0; n < 3; n++){
    int cb = bx * 192 + wc * 48 + n * 16;     // wave-uniform frag col base
    if (cb < 2048){
      float sc = (cb < 1024) ? 0.1803368801111f : 1.0f;  // 0.125*log2(e) on Q
#pragma unroll
      for (int m = 0; m < 4; m++){
        int row = row0 + m * 16;
#pragma unroll
        for (int r = 0; r < 4; r++)
          QK[(size_t)(row + r) * 2048 + cb + li] = f2bf(acc[m][n][r] * sc);
      }
    } else {
      int vc = cb + li - 2048;                // v-column 0..1023
      int hh = vc >> 6, dd = vc & 63;
#pragma unroll
      for (int m = 0; m < 4; m++){
        int mtok = (row0 + m * 16) & 1023;
        uint2 cv;
        cv.x = pkrtz_u32(acc[m][n][0], acc[m][n][1]);
        cv.y = pkrtz_u32(acc[m][n][2], acc[m][n][3]);
        *(uint2*)(Vt + ((size_t)(bb16 + hh) * 64 + dd) * 1024 + mtok) = cv;
      }
    }
  }
}

// ---------------- kernel 3: flash attention ----------------
// block = (b, h, qb): 4 waves x 32 q = 128 q per block; m-tiles of 64.
// 1024 blocks = 4/CU x 256 CU = one round; launch_bounds(256,4).
// Each wave: 2 q-groups (u=0,1) of 16 q; K/V frag reads shared across u ->
// LDS bytes per q halved vs R3. All layouts identical to the verified R3 kernel.
// XCD swizzle: bh = id&127 so q-blocks of one (b,h) share id%8 (same XCD L2).
__global__ __launch_bounds__(256, 4) void attn(const unsigned short* __restrict__ QK,
                                               const unsigned short* __restrict__ Vt,
                                               float* __restrict__ Out){
  __shared__ __align__(16) unsigned short Kbuf[64 * 64];   // bf16
  __shared__ __align__(16) unsigned short Vbuf[64 * 64];   // fp16
  int id = blockIdx.x;                  // 1024
  int bh = id & 127, qb = id >> 7;      // qb 0..7
  int b = bh >> 4, h = bh & 15;
  int w = threadIdx.x >> 6, lane = threadIdx.x & 63;
  int g = lane >> 4, li = lane & 15;
  int lrow = lane >> 3, lcol = lane & 7;
  int scol = ((lcol ^ lrow) & 7) * 8;   // XOR-swizzled staging column

  // Q B-frags (bf16), two q-groups: lane li holds col q, k = c*32 + g*8 + j
  frag_u qf[2][2];
#pragma unroll
  for (int u = 0; u < 2; u++){
    int tok = b * 1024 + qb * 128 + w * 32 + u * 16 + li;
    const unsigned short* qp = QK + (size_t)tok * 2048 + h * 64 + g * 8;
    qf[u][0].u4 = *(const uint4*)(qp);
    qf[u][1].u4 = *(const uint4*)(qp + 32);
  }

  f32x4 o[2][4] = {};          // O^T tiles per q-group: row v = tv*16+g*4+r, col q = li
  f32x4 osum[2] = {};          // ones-row PV accumulators
  const f32x4 bias = {-10.f, -10.f, -10.f, -10.f};   // fp16-overflow guard
  pfrag_u ones;                // all-ones fp16 A-frag for the denominator MFMA
  ones.u[0] = 0x3c003c00u; ones.u[1] = 0x3c003c00u;

  const unsigned short* Kg = QK + (size_t)b * 1024 * 2048 + 1024 + h * 64;
  const unsigned short* Vg = Vt + (size_t)bh * 65536;

  for (int mt = 0; mt < 16; mt++){
    int m0 = mt * 64;
    __syncthreads();                    // K/V LDS reuse barrier
    for (int i = 0; i < 2; i++){
      int idx = w * 2 + i;              // 0..7
      int row = idx * 8 + lrow;         // 0..63
      gl_lds16(Kg + (size_t)(m0 + row) * 2048 + scol, Kbuf + idx * 512);
      gl_lds16(Vg + row * 1024 + m0 + scol,           Vbuf + idx * 512);
    }
    __syncthreads();

    // S^T = K Q^T - 10 : A-frag = K rows (m) from LDS, B-frag = Q (regs).
    // Each kf read feeds BOTH q-groups (the LDS-traffic halving).
    f32x4 s[2][4];
#pragma unroll
    for (int u = 0; u < 2; u++)
#pragma unroll
      for (int t = 0; t < 4; t++) s[u][t] = bias;
#pragma unroll
    for (int t = 0; t < 4; t++){
#pragma unroll
      for (int c = 0; c < 2; c++){
        frag_u kf;
        kf.u4 = *(const uint4*)(Kbuf + (t * 16 + li) * 64 + ((((c << 2) + g) ^ (li & 7)) << 3));
        s[0][t] = __builtin_amdgcn_mfma_f32_16x16x32_bf16(kf.f, qf[0][c].f, s[0][t], 0, 0, 0);
        s[1][t] = __builtin_amdgcn_mfma_f32_16x16x32_bf16(kf.f, qf[1][c].f, s[1][t], 0, 0, 0);
      }
    }

    // P = exp2(S^T); lane holds P[q=li][m = t*16 + g*4 + r] == B-frag(k = g*4+e)
    // of mfma_f32_16x16x16f16 for k-chunk t. Pack straight into registers.
    pfrag_u pf[2][4];
#pragma unroll
    for (int u = 0; u < 2; u++){
#pragma unroll
      for (int t = 0; t < 4; t++){
        float p0 = __builtin_exp2f(s[u][t][0]);
        float p1 = __builtin_exp2f(s[u][t][1]);
        float p2 = __builtin_exp2f(s[u][t][2]);
        float p3 = __builtin_exp2f(s[u][t][3]);
        pf[u][t].u[0] = pkrtz_u32(p0, p1);
        pf[u][t].u[1] = pkrtz_u32(p2, p3);
      }
    }

    // O^T += V^T P^T ; denominator row via ones-A MFMA (column sums of P).
#pragma unroll
    for (int t = 0; t < 4; t++){
      osum[0] = __builtin_amdgcn_mfma_f32_16x16x16f16(ones.f, pf[0][t].f, osum[0], 0, 0, 0);
      osum[1] = __builtin_amdgcn_mfma_f32_16x16x16f16(ones.f, pf[1][t].f, osum[1], 0, 0, 0);
    }
#pragma unroll
    for (int tv = 0; tv < 4; tv++){
#pragma unroll
      for (int t = 0; t < 4; t++){
        int gg = ((t * 2 + (g >> 1)) ^ (li & 7));
        vfrag_u vf;                      // one vf read feeds BOTH q-groups
        vf.u2 = *(const uint2*)(Vbuf + (tv * 16 + li) * 64 + gg * 8 + (g & 1) * 4);
        o[0][tv] = __builtin_amdgcn_mfma_f32_16x16x16f16(vf.f, pf[0][t].f, o[0][tv], 0, 0, 0);
        o[1][tv] = __builtin_amdgcn_mfma_f32_16x16x16f16(vf.f, pf[1][t].f, o[1][tv], 0, 0, 0);
      }
    }
  }

  // epilogue per q-group: lane holds O^T[v = tv*16+g*4+r][q=li] -> Out[b,q,h,v]
#pragma unroll
  for (int u = 0; u < 2; u++){
    float inv = 1.f / osum[u][0];
    int tok = b * 1024 + qb * 128 + w * 32 + u * 16 + li;
    float* op = Out + (size_t)tok * 1024 + h * 64 + g * 4;
#pragma unroll
    for (int tv = 0; tv < 4; tv++){
      float4 v4;
      v4.x = o[u][tv][0] * inv; v4.y = o[u][tv][1] * inv;
      v4.z = o[u][tv][2] * inv; v4.w = o[u][tv][3] * inv;
      *(float4*)(op + tv * 16) = v4;
    }
  }
}

extern "C" void kernel_launch(void* const* d_in, const int* in_sizes, int n_in,
                              void* d_out, int out_size, void* d_ws, size_t ws_size,
                              hipStream_t stream) {
  const float* X  = (const float*)d_in[0];
  const float* Wq = (const float*)d_in[1];
  const float* Wk = (const float*)d_in[2];
  const float* Wv = (const float*)d_in[3];
  float* Out = (float*)d_out;
  char* ws = (char*)d_ws;
  // workspace layout (bytes): Xb 16MB | Wt 6MB | QK 32MB | Vt 16MB  (total 70MB)
  unsigned short* Xb = (unsigned short*)(ws);
  unsigned short* Wt = (unsigned short*)(ws + (size_t)16 * 1024 * 1024);
  unsigned short* QK = (unsigned short*)(ws + (size_t)22 * 1024 * 1024);
  unsigned short* Vt = (unsigned short*)(ws + (size_t)54 * 1024 * 1024);

  cast_all<<<8960, 256, 0, stream>>>(X, Wq, Wk, Wv, Xb, Wt);
  gemm_qkv<<<512, 1024, 0, stream>>>(Xb, Wt, QK, Vt);
  attn    <<<1024, 256, 0, stream>>>(QK, Vt, Out);
}

// Round 9
// 191.917 us; speedup vs baseline: 2.5221x; 1.0855x over previous
//
#include <hip/hip_runtime.h>
#include <stdint.h>

// B=8, W=1024, D=1024, H=16, KD=VD=64
// QK buffer: rows = token (8192), cols = proj*1024 + h*64 + d (2048; Q,K only, bf16)
// Vt[bh][d][m] fp16, written transposed from the GEMM epilogue.
// Q pre-scaled by 0.125*log2(e) (softmax in exp2 domain).
//
// gemm_qkv: BM=256 BN=192 BK=64, 16 waves (4Mx4N grid, 64x48 per wave),
// 4 waves/SIMD; 2 phases per K-tile; 3-bit XOR swizzle (0 conflicts, R2);
// counted vmcnt (never drain-0 in loop).
//
// attn R9: ONE change vs R8 — raw v_exp_f32 for the softmax exp2.
// R8 diagnosis: VALUBusy 51% = ~160 VALU instrs/wave-tile, of which ~128 are
// clang's denormal-fixup expansion of __builtin_exp2f (4-5 instrs each).
// __builtin_amdgcn_exp2f emits the single instruction (denorm-flush semantics
// are harmless: denormal P contributes ~0 to the sums). VALU was the binding
// pipe (51% > MFMA 43%); LDS-BW theory refuted by R8 (halved traffic, 0 delta).

using bf16x8 = __attribute__((ext_vector_type(8))) __bf16;
using f32x4  = __attribute__((ext_vector_type(4))) float;
using f16x4  = __attribute__((ext_vector_type(4))) _Float16;

union frag_u  { uint4 u4; bf16x8 f; };
union vfrag_u { uint2 u2; f16x4 f; };
union pfrag_u { unsigned int u[2]; f16x4 f; };

__device__ inline unsigned short f2bf(float x){
  unsigned int u = __float_as_uint(x);
  u += 0x7fffu + ((u >> 16) & 1u);      // round-to-nearest-even
  return (unsigned short)(u >> 16);
}

__device__ inline unsigned int pkrtz_u32(float a, float b){
  auto r = __builtin_amdgcn_cvt_pkrtz(a, b);   // __fp16 ext_vector(2)
  unsigned int u; __builtin_memcpy(&u, &r, 4); return u;
}

__device__ inline float fexp2(float x){
#if __has_builtin(__builtin_amdgcn_exp2f)
  return __builtin_amdgcn_exp2f(x);     // single v_exp_f32, no denorm fixup
#else
  float r; asm("v_exp_f32 %0, %1\n\ts_nop 0" : "=v"(r) : "v"(x)); return r;
#endif
}

__device__ inline void gl_lds16(const void* g, void* l){
  __builtin_amdgcn_global_load_lds(
      (const __attribute__((address_space(1))) void*)g,
      (__attribute__((address_space(3))) void*)l, 16, 0, 0);
}

#define SBAR() do{ asm volatile("" ::: "memory"); __builtin_amdgcn_s_barrier(); asm volatile("" ::: "memory"); }while(0)
#define VMC(n)  asm volatile("s_waitcnt vmcnt(" #n ")" ::: "memory")

// ---------------- kernel 1: fused input & weight cast ----------------
// blocks [0,8192): X fp32->bf16.  blocks [8192,8960): W transpose+cast.
__global__ void cast_all(const float* __restrict__ X,
                         const float* __restrict__ Wq, const float* __restrict__ Wk,
                         const float* __restrict__ Wv,
                         unsigned short* __restrict__ Xb,
                         unsigned short* __restrict__ Wt){
  __shared__ float tile[64][65];
  int bid = blockIdx.x;
  if (bid < 8192){
    int i = (bid * 256 + threadIdx.x) * 4;
    float4 v = *(const float4*)(X + i);
    ushort4 o;
    o.x = f2bf(v.x); o.y = f2bf(v.y); o.z = f2bf(v.z); o.w = f2bf(v.w);
    *(ushort4*)(Xb + i) = o;
    return;
  }
  int id = bid - 8192;            // 0..767
  int proj = id >> 8;
  int rem  = id & 255;
  int kt = rem & 15, nt = rem >> 4;
  const float* Wsrc = (proj == 0) ? Wq : ((proj == 1) ? Wk : Wv);
  int k0 = kt * 64, n0 = nt * 64;
  int tx = threadIdx.x & 63, ty = threadIdx.x >> 6;   // ty 0..3
  for (int i = 0; i < 16; i++){
    int k = i * 4 + ty;
    tile[k][tx] = Wsrc[(k0 + k) * 1024 + n0 + tx];
  }
  __syncthreads();
  for (int i = 0; i < 16; i++){
    int n = i * 4 + ty;
    Wt[(proj * 1024 + n0 + n) * 1024 + k0 + tx] = f2bf(tile[tx][n]);
  }
}

// ---------------- kernel 2: fused QKV GEMM ----------------
__global__ __launch_bounds__(1024, 4) void gemm_qkv(
    const unsigned short* __restrict__ Xb,
    const unsigned short* __restrict__ Wt,
    unsigned short* __restrict__ QK,
    unsigned short* __restrict__ Vt){
  __shared__ __align__(16) char Abuf[2][32768];   // [buf][256 rows x 64 k] bf16, swizzled
  __shared__ __align__(16) char Bbuf[2][24576];   // [buf][192 rows x 64 k] bf16, swizzled

  int bid = blockIdx.x;                      // 512
  int tau = (bid & 7) * 64 + (bid >> 3);     // XCD swizzle (512 % 8 == 0, bijective)
  int by = tau >> 4, bx = tau & 15;          // by: m-tile (32), bx: n-tile (16)
  int tid = threadIdx.x;
  int w = tid >> 6, lane = tid & 63;
  int li = lane & 15, g = lane >> 4;
  int lrow = lane >> 3;                      // 0..7 (dest row within 8-lane cluster)
  int wr = w >> 2, wc = w & 3;               // 4 x 4 wave grid, wave tile 64x48
  int wu = __builtin_amdgcn_readfirstlane(w);

  // staging source offsets (elements): inverse of byte ^= (row&7)<<4.
  int xcol = ((lane & 7) ^ lrow) << 3;
  int aoff0 = (by * 256 + w * 8 + lrow) * 1024 + xcol;          // A segs 0..15
  int aoff1 = (by * 256 + (16 + w) * 8 + lrow) * 1024 + xcol;   // A segs 16..31
  int bseg0 = (w < 8) ? w : (w + 8);         // B segs: w<8 -> {w, w+8}; w>=8 -> {w+8}
  int bseg1 = w + 8;
  int boff0 = (bx * 192 + bseg0 * 8 + lrow) * 1024 + xcol;
  int boff1 = (bx * 192 + bseg1 * 8 + lrow) * 1024 + xcol;      // only w<8

  // ds_read addressing (bytes): physical = row*128 + ((kk*64+g*16) ^ ((row&7)<<4))
  int swz  = (li & 7) << 4;
  int colA0 = (g * 16) ^ swz;
  int colA1 = (64 + g * 16) ^ swz;
  int aBase = (wr * 64 + li) * 128;
  int bBase = (wc * 48 + li) * 128;

  f32x4 acc[4][3] = {};
  frag_u bfr[3][2], af[2][2];

#define LDB(buf) do{ \
  _Pragma("unroll") for (int n = 0; n < 3; n++){ \
    bfr[n][0].u4 = *(const uint4*)&Bbuf[buf][bBase + n * 2048 + colA0]; \
    bfr[n][1].u4 = *(const uint4*)&Bbuf[buf][bBase + n * 2048 + colA1]; } }while(0)
#define LDA2(buf, m0) do{ \
  af[0][0].u4 = *(const uint4*)&Abuf[buf][aBase + (m0)     * 2048 + colA0]; \
  af[0][1].u4 = *(const uint4*)&Abuf[buf][aBase + (m0)     * 2048 + colA1]; \
  af[1][0].u4 = *(const uint4*)&Abuf[buf][aBase + (m0 + 1) * 2048 + colA0]; \
  af[1][1].u4 = *(const uint4*)&Abuf[buf][aBase + (m0 + 1) * 2048 + colA1]; }while(0)
#define MFMA6(P) do{ __builtin_amdgcn_s_setprio(1); \
  _Pragma("unroll") for (int kk = 0; kk < 2; kk++) \
  _Pragma("unroll") for (int i = 0; i < 2; i++) \
  _Pragma("unroll") for (int n = 0; n < 3; n++) \
    acc[(P) + i][n] = __builtin_amdgcn_mfma_f32_16x16x32_bf16( \
        af[i][kk].f, bfr[n][kk].f, acc[(P) + i][n], 0, 0, 0); \
  __builtin_amdgcn_s_setprio(0); }while(0)

  // prologue: B(0), A(0), B(1); wait so tile0 resident, B(1) in flight
  gl_lds16(Wt + boff0, &Bbuf[0][bseg0 * 1024]);
  if (wu < 8) gl_lds16(Wt + boff1, &Bbuf[0][bseg1 * 1024]);
  gl_lds16(Xb + aoff0, &Abuf[0][w * 1024]);
  gl_lds16(Xb + aoff1, &Abuf[0][(16 + w) * 1024]);
  gl_lds16(Wt + boff0 + 64, &Bbuf[1][bseg0 * 1024]);
  if (wu < 8){
    gl_lds16(Wt + boff1 + 64, &Bbuf[1][bseg1 * 1024]);
    VMC(2);
  } else {
    VMC(1);
  }
  SBAR();

  for (int t = 0; t < 16; ++t){
    int cur = t & 1, nxt = cur ^ 1;
    // ---- phase 0: read B + A(mi 0-1), stage A(t+1), MFMA mi 0-1
    LDB(cur);
    LDA2(cur, 0);
    if (t < 15){
      gl_lds16(Xb + aoff0 + (t + 1) * 64, &Abuf[nxt][w * 1024]);
      gl_lds16(Xb + aoff1 + (t + 1) * 64, &Abuf[nxt][(16 + w) * 1024]);
    }
    MFMA6(0);                 // consumes all phase-0 ds_reads before barrier
    SBAR();
    // ---- phase 1: read A(mi 2-3), stage B(t+2) (Bbuf[cur]: B-reads all done
    // at phase 0 and every wave is past the phase-0 barrier -> safe), MFMA mi 2-3
    LDA2(cur, 2);
    if (t < 14){
      gl_lds16(Wt + boff0 + (t + 2) * 64, &Bbuf[cur][bseg0 * 1024]);
      if (wu < 8) gl_lds16(Wt + boff1 + (t + 2) * 64, &Bbuf[cur][bseg1 * 1024]);
    }
    MFMA6(2);
    if (t < 14){
      if (wu < 8) { VMC(2); } else { VMC(1); }   // leave only B(t+2) in flight
    } else if (t == 14) {
      VMC(0);                                    // final drain: tile 15 resident
    }
    SBAR();
  }
#undef LDB
#undef LDA2
#undef MFMA6

  // epilogue: frag (mi,n): row = by*256 + wr*64 + mi*16 + g*4 + r, col = cb + li
  int row0 = by * 256 + wr * 64 + g * 4;
  int bb16 = (by >> 2) * 16;
#pragma unroll
  for (int n = 0; n < 3; n++){
    int cb = bx * 192 + wc * 48 + n * 16;     // wave-uniform frag col base
    if (cb < 2048){
      float sc = (cb < 1024) ? 0.1803368801111f : 1.0f;  // 0.125*log2(e) on Q
#pragma unroll
      for (int m = 0; m < 4; m++){
        int row = row0 + m * 16;
#pragma unroll
        for (int r = 0; r < 4; r++)
          QK[(size_t)(row + r) * 2048 + cb + li] = f2bf(acc[m][n][r] * sc);
      }
    } else {
      int vc = cb + li - 2048;                // v-column 0..1023
      int hh = vc >> 6, dd = vc & 63;
#pragma unroll
      for (int m = 0; m < 4; m++){
        int mtok = (row0 + m * 16) & 1023;
        uint2 cv;
        cv.x = pkrtz_u32(acc[m][n][0], acc[m][n][1]);
        cv.y = pkrtz_u32(acc[m][n][2], acc[m][n][3]);
        *(uint2*)(Vt + ((size_t)(bb16 + hh) * 64 + dd) * 1024 + mtok) = cv;
      }
    }
  }
}

// ---------------- kernel 3: flash attention ----------------
// block = (b, h, qb): 4 waves x 32 q = 128 q per block; m-tiles of 64.
// 1024 blocks = 4/CU x 256 CU = one round; launch_bounds(256,4).
// Each wave: 2 q-groups (u=0,1) of 16 q; K/V frag reads shared across u.
// Softmax exp2 via raw v_exp_f32 (R9).
// XCD swizzle: bh = id&127 so q-blocks of one (b,h) share id%8 (same XCD L2).
__global__ __launch_bounds__(256, 4) void attn(const unsigned short* __restrict__ QK,
                                               const unsigned short* __restrict__ Vt,
                                               float* __restrict__ Out){
  __shared__ __align__(16) unsigned short Kbuf[64 * 64];   // bf16
  __shared__ __align__(16) unsigned short Vbuf[64 * 64];   // fp16
  int id = blockIdx.x;                  // 1024
  int bh = id & 127, qb = id >> 7;      // qb 0..7
  int b = bh >> 4, h = bh & 15;
  int w = threadIdx.x >> 6, lane = threadIdx.x & 63;
  int g = lane >> 4, li = lane & 15;
  int lrow = lane >> 3, lcol = lane & 7;
  int scol = ((lcol ^ lrow) & 7) * 8;   // XOR-swizzled staging column

  // Q B-frags (bf16), two q-groups: lane li holds col q, k = c*32 + g*8 + j
  frag_u qf[2][2];
#pragma unroll
  for (int u = 0; u < 2; u++){
    int tok = b * 1024 + qb * 128 + w * 32 + u * 16 + li;
    const unsigned short* qp = QK + (size_t)tok * 2048 + h * 64 + g * 8;
    qf[u][0].u4 = *(const uint4*)(qp);
    qf[u][1].u4 = *(const uint4*)(qp + 32);
  }

  f32x4 o[2][4] = {};          // O^T tiles per q-group: row v = tv*16+g*4+r, col q = li
  f32x4 osum[2] = {};          // ones-row PV accumulators
  const f32x4 bias = {-10.f, -10.f, -10.f, -10.f};   // fp16-overflow guard
  pfrag_u ones;                // all-ones fp16 A-frag for the denominator MFMA
  ones.u[0] = 0x3c003c00u; ones.u[1] = 0x3c003c00u;

  const unsigned short* Kg = QK + (size_t)b * 1024 * 2048 + 1024 + h * 64;
  const unsigned short* Vg = Vt + (size_t)bh * 65536;

  for (int mt = 0; mt < 16; mt++){
    int m0 = mt * 64;
    __syncthreads();                    // K/V LDS reuse barrier
    for (int i = 0; i < 2; i++){
      int idx = w * 2 + i;              // 0..7
      int row = idx * 8 + lrow;         // 0..63
      gl_lds16(Kg + (size_t)(m0 + row) * 2048 + scol, Kbuf + idx * 512);
      gl_lds16(Vg + row * 1024 + m0 + scol,           Vbuf + idx * 512);
    }
    __syncthreads();

    // S^T = K Q^T - 10 : A-frag = K rows (m) from LDS, B-frag = Q (regs).
    // Each kf read feeds BOTH q-groups.
    f32x4 s[2][4];
#pragma unroll
    for (int u = 0; u < 2; u++)
#pragma unroll
      for (int t = 0; t < 4; t++) s[u][t] = bias;
#pragma unroll
    for (int t = 0; t < 4; t++){
#pragma unroll
      for (int c = 0; c < 2; c++){
        frag_u kf;
        kf.u4 = *(const uint4*)(Kbuf + (t * 16 + li) * 64 + ((((c << 2) + g) ^ (li & 7)) << 3));
        s[0][t] = __builtin_amdgcn_mfma_f32_16x16x32_bf16(kf.f, qf[0][c].f, s[0][t], 0, 0, 0);
        s[1][t] = __builtin_amdgcn_mfma_f32_16x16x32_bf16(kf.f, qf[1][c].f, s[1][t], 0, 0, 0);
      }
    }

    // P = exp2(S^T); lane holds P[q=li][m = t*16 + g*4 + r] == B-frag(k = g*4+e)
    // of mfma_f32_16x16x16f16 for k-chunk t. Pack straight into registers.
    pfrag_u pf[2][4];
#pragma unroll
    for (int u = 0; u < 2; u++){
#pragma unroll
      for (int t = 0; t < 4; t++){
        float p0 = fexp2(s[u][t][0]);
        float p1 = fexp2(s[u][t][1]);
        float p2 = fexp2(s[u][t][2]);
        float p3 = fexp2(s[u][t][3]);
        pf[u][t].u[0] = pkrtz_u32(p0, p1);
        pf[u][t].u[1] = pkrtz_u32(p2, p3);
      }
    }

    // O^T += V^T P^T ; denominator row via ones-A MFMA (column sums of P).
#pragma unroll
    for (int t = 0; t < 4; t++){
      osum[0] = __builtin_amdgcn_mfma_f32_16x16x16f16(ones.f, pf[0][t].f, osum[0], 0, 0, 0);
      osum[1] = __builtin_amdgcn_mfma_f32_16x16x16f16(ones.f, pf[1][t].f, osum[1], 0, 0, 0);
    }
#pragma unroll
    for (int tv = 0; tv < 4; tv++){
#pragma unroll
      for (int t = 0; t < 4; t++){
        int gg = ((t * 2 + (g >> 1)) ^ (li & 7));
        vfrag_u vf;                      // one vf read feeds BOTH q-groups
        vf.u2 = *(const uint2*)(Vbuf + (tv * 16 + li) * 64 + gg * 8 + (g & 1) * 4);
        o[0][tv] = __builtin_amdgcn_mfma_f32_16x16x16f16(vf.f, pf[0][t].f, o[0][tv], 0, 0, 0);
        o[1][tv] = __builtin_amdgcn_mfma_f32_16x16x16f16(vf.f, pf[1][t].f, o[1][tv], 0, 0, 0);
      }
    }
  }

  // epilogue per q-group: lane holds O^T[v = tv*16+g*4+r][q=li] -> Out[b,q,h,v]
#pragma unroll
  for (int u = 0; u < 2; u++){
    float inv = 1.f / osum[u][0];
    int tok = b * 1024 + qb * 128 + w * 32 + u * 16 + li;
    float* op = Out + (size_t)tok * 1024 + h * 64 + g * 4;
#pragma unroll
    for (int tv = 0; tv < 4; tv++){
      float4 v4;
      v4.x = o[u][tv][0] * inv; v4.y = o[u][tv][1] * inv;
      v4.z = o[u][tv][2] * inv; v4.w = o[u][tv][3] * inv;
      *(float4*)(op + tv * 16) = v4;
    }
  }
}

extern "C" void kernel_launch(void* const* d_in, const int* in_sizes, int n_in,
                              void* d_out, int out_size, void* d_ws, size_t ws_size,
                              hipStream_t stream) {
  const float* X  = (const float*)d_in[0];
  const float* Wq = (const float*)d_in[1];
  const float* Wk = (const float*)d_in[2];
  const float* Wv = (const float*)d_in[3];
  float* Out = (float*)d_out;
  char* ws = (char*)d_ws;
  // workspace layout (bytes): Xb 16MB | Wt 6MB | QK 32MB | Vt 16MB  (total 70MB)
  unsigned short* Xb = (unsigned short*)(ws);
  unsigned short* Wt = (unsigned short*)(ws + (size_t)16 * 1024 * 1024);
  unsigned short* QK = (unsigned short*)(ws + (size_t)22 * 1024 * 1024);
  unsigned short* Vt = (unsigned short*)(ws + (size_t)54 * 1024 * 1024);

  cast_all<<<8960, 256, 0, stream>>>(X, Wq, Wk, Wv, Xb, Wt);
  gemm_qkv<<<512, 1024, 0, stream>>>(Xb, Wt, QK, Vt);
  attn    <<<1024, 256, 0, stream>>>(QK, Vt, Out);
}